// Round 7
// baseline (10388.458 us; speedup 1.0000x reference)
//
#include <hip/hip_runtime.h>
#include <hip/hip_cooperative_groups.h>

namespace cg = cooperative_groups;

#define NB 64
#define NS 256
#define NH 1024
#define NE 512
#define NV 10000
#define NT 64
#define ND 512
#define NEH 1536

typedef __attribute__((ext_vector_type(8))) short bf16x8;
typedef __attribute__((ext_vector_type(4))) float f32x4;

__device__ __forceinline__ short F2B(float f) {
  unsigned u = __float_as_uint(f);
  return (short)((u + 0x7fffu + ((u >> 16) & 1u)) >> 16);
}
__device__ __forceinline__ float B2F(short s) {
  return __uint_as_float(((unsigned)(unsigned short)s) << 16);
}
__device__ __forceinline__ float ftanh(float x) {
  float e = __expf(2.f * x);                 // inf for big x -> rcp -> 0 -> 1
  return 1.f - 2.f * __builtin_amdgcn_rcpf(e + 1.f);
}

#define GLD16(src, dst)                                                        \
  __builtin_amdgcn_global_load_lds(                                            \
      (const __attribute__((address_space(1))) void*)(src),                    \
      (__attribute__((address_space(3))) void*)(dst), 16, 0, 0)

// ---------------------------------------------------------------------------
// Phase A: q = hcur @ Wa^T. One block unit = (M=64, N=16, K=1024), BK=128,
// 3-deep LDS pipeline, counted vmcnt, raw barriers. blk in [0,64).
// ---------------------------------------------------------------------------
__device__ __forceinline__ void q_phase(const short* __restrict__ hcur,
                                        const short* __restrict__ Wa_h,
                                        float* __restrict__ qout, int blk,
                                        char* smem)
{
  const int tid = threadIdx.x, lane = tid & 63, w = tid >> 6;
  const int kg = lane >> 4, rl = lane & 15;
  const int n0 = blk << 4;
  const short* Wbase = Wa_h + (size_t)n0 * NH;

  auto stage = [&](int it, int buf) {
    char* dst = smem + buf * 20480;
#pragma unroll
    for (int g = 0; g < 4; ++g) {
      int row = (g << 4) + (w << 2) + kg;
      int c = rl ^ (row & 15);
      int k = (it << 7) + (c << 3);
      GLD16(hcur + (size_t)row * NH + k, dst + (g << 12) + (w << 10));
    }
    {
      int rowB = (w << 2) + kg;
      int cB = rl ^ rowB;
      int kB = (it << 7) + (cB << 3);
      GLD16(Wbase + (size_t)rowB * NH + kB, dst + 16384 + (w << 10));
    }
  };

  stage(0, 0); stage(1, 1); stage(2, 2);
  f32x4 acc = {};
  int buf = 0;
  for (int it = 0; it < 8; ++it) {
    if (it < 6)       asm volatile("s_waitcnt vmcnt(10)" ::: "memory");
    else if (it == 6) asm volatile("s_waitcnt vmcnt(5)" ::: "memory");
    else              asm volatile("s_waitcnt vmcnt(0)" ::: "memory");
    __builtin_amdgcn_s_barrier();
    __builtin_amdgcn_sched_barrier(0);
    const short* As = (const short*)(smem + buf * 20480);
    const short* Bs = (const short*)(smem + buf * 20480 + 16384);
    const int rowA = (w << 4) + rl;
#pragma unroll
    for (int kk = 0; kk < 4; ++kk) {
      int chunk = (kk << 2) | kg;
      bf16x8 af = *((const bf16x8*)As + ((rowA << 4) | (chunk ^ (rowA & 15))));
      bf16x8 bf = *((const bf16x8*)Bs + ((rl << 4) | (chunk ^ rl)));
      acc = __builtin_amdgcn_mfma_f32_16x16x32_bf16(af, bf, acc, 0, 0, 0);
    }
    __builtin_amdgcn_sched_barrier(0);
    __builtin_amdgcn_s_barrier();
    if (it + 3 < 8) stage(it + 3, buf);
    buf = (buf == 2) ? 0 : buf + 1;
  }
#pragma unroll
  for (int r = 0; r < 4; ++r)
    qout[(size_t)((w << 4) + (kg << 2) + r) * NH + n0 + rl] = acc[r];
}

// ---------------------------------------------------------------------------
// Phase B: scores. blk in [0,256): b = blk>>2, s-quarter = blk&3.
// Wave w handles 16 s values; lane l covers h=[l*16,l*16+16) in registers.
// ---------------------------------------------------------------------------
__device__ __forceinline__ void score_phase(
    const float* __restrict__ qbuf, const short* __restrict__ Uk,
    const float* __restrict__ Va, const unsigned char* __restrict__ mask,
    float* __restrict__ scbuf, int blk)
{
  const int tid = threadIdx.x, lane = tid & 63, w = tid >> 6;
  const int b = blk >> 2, sq = blk & 3;
  float qv[16], vv[16];
  {
    const float* qp = qbuf + (size_t)b * NH + (lane << 4);
    const float* vp = Va + (lane << 4);
#pragma unroll
    for (int j4 = 0; j4 < 4; ++j4) {
      float4 a = *(const float4*)(qp + (j4 << 2));
      float4 c = *(const float4*)(vp + (j4 << 2));
      qv[(j4 << 2) + 0] = a.x; qv[(j4 << 2) + 1] = a.y;
      qv[(j4 << 2) + 2] = a.z; qv[(j4 << 2) + 3] = a.w;
      vv[(j4 << 2) + 0] = c.x; vv[(j4 << 2) + 1] = c.y;
      vv[(j4 << 2) + 2] = c.z; vv[(j4 << 2) + 3] = c.w;
    }
  }
#pragma unroll 1
  for (int i = 0; i < 16; ++i) {
    const int s = (sq << 6) + (w << 4) + i;
    const short* up = Uk + ((size_t)b * NS + s) * NH + (lane << 4);
    bf16x8 u0 = ((const bf16x8*)up)[0];
    bf16x8 u1 = ((const bf16x8*)up)[1];
    float a = 0.f;
#pragma unroll
    for (int j = 0; j < 8; ++j) a += vv[j] * ftanh(qv[j] + B2F(u0[j]));
#pragma unroll
    for (int j = 0; j < 8; ++j) a += vv[8 + j] * ftanh(qv[8 + j] + B2F(u1[j]));
#pragma unroll
    for (int o = 32; o; o >>= 1) a += __shfl_down(a, o);
    if (lane == 0) scbuf[b * NS + s] = mask[b * NS + s] ? -__builtin_inff() : a;
  }
}

// ---------------------------------------------------------------------------
// Phase C: softmax + ctx. blk in [0,256): b = blk>>2, qh = blk&3.
// smem usage: ws[256] @0, red[4] @1024, red4[4][64] float4 @2048 (6KB total).
// ---------------------------------------------------------------------------
__device__ __forceinline__ void ctx_phase(
    const float* __restrict__ sc, const short* __restrict__ enc_h,
    const float* __restrict__ enc_f, int use_h, short* __restrict__ Xt,
    float* __restrict__ attn_out, int t, int blk, char* smem)
{
  const int tid = threadIdx.x;
  const int b = blk >> 2, qh = blk & 3;
  float* ws = (float*)smem;
  float* red = (float*)(smem + 1024);
  float4* red4 = (float4*)(smem + 2048);
  float v = sc[b * NS + tid];
  float m = v;
#pragma unroll
  for (int o = 32; o; o >>= 1) m = fmaxf(m, __shfl_down(m, o));
  if ((tid & 63) == 0) red[tid >> 6] = m;
  __syncthreads();
  m = fmaxf(fmaxf(red[0], red[1]), fmaxf(red[2], red[3]));
  float e = __expf(v - m);
  float su = e;
#pragma unroll
  for (int o = 32; o; o >>= 1) su += __shfl_down(su, o);
  __syncthreads();
  if ((tid & 63) == 0) red[tid >> 6] = su;
  __syncthreads();
  su = red[0] + red[1] + red[2] + red[3];
  float wgt = e / su;
  ws[tid] = wgt;
  if (qh == 0) attn_out[((size_t)b * NT + t) * NS + tid] = wgt;
  __syncthreads();
  const int w = tid >> 6, l = tid & 63;
  const int h = (qh << 8) + (l << 2);
  const int s0 = w << 6;
  float4 a = make_float4(0.f, 0.f, 0.f, 0.f);
  if (use_h) {
    const short* ep = enc_h + ((size_t)b * NS + s0) * NH + h;
    for (int s = 0; s < 64; ++s) {
      short4 vv = *(const short4*)(ep + (size_t)s * NH);
      float wv = ws[s0 + s];
      a.x += wv * B2F(vv.x); a.y += wv * B2F(vv.y);
      a.z += wv * B2F(vv.z); a.w += wv * B2F(vv.w);
    }
  } else {
    const float* ep = enc_f + ((size_t)b * NS + s0) * NH + h;
    for (int s = 0; s < 64; ++s) {
      float4 vv = *(const float4*)(ep + (size_t)s * NH);
      float wv = ws[s0 + s];
      a.x += wv * vv.x; a.y += wv * vv.y; a.z += wv * vv.z; a.w += wv * vv.w;
    }
  }
  red4[(w << 6) + l] = a;
  __syncthreads();
  if (tid < 64) {
    float4 r0 = red4[tid], r1 = red4[64 + tid], r2 = red4[128 + tid],
           r3 = red4[192 + tid];
    short4 o;
    o.x = F2B(r0.x + r1.x + r2.x + r3.x);
    o.y = F2B(r0.y + r1.y + r2.y + r3.y);
    o.z = F2B(r0.z + r1.z + r2.z + r3.z);
    o.w = F2B(r0.w + r1.w + r2.w + r3.w);
    *(short4*)(Xt + (size_t)b * NEH + NE + (qh << 8) + (tid << 2)) = o;
  }
}

// ---------------------------------------------------------------------------
// Phase D: gates GEMM + LSTM cell. blk in [0,256): dir = blk>>7, gi = blk&127.
// (M=64, N=16 permuted gate cols, K=2048), BK=128, 3-deep, counted vmcnt.
// ---------------------------------------------------------------------------
__device__ __forceinline__ void gates_phase(
    const short* __restrict__ Xt, const short* __restrict__ hcur,
    const short* __restrict__ Wcomb, const float* __restrict__ bperm,
    const float* __restrict__ cq_old, float* __restrict__ hq_f,
    float* __restrict__ cq_new, short* __restrict__ hnext, int blk, char* smem)
{
  const int tid = threadIdx.x, lane = tid & 63, w = tid >> 6;
  const int kg = lane >> 4, rl = lane & 15;
  const int dir = blk >> 7, gi = blk & 127;
  const int hoff = dir << 9;
  const short* Wbase = Wcomb + (((size_t)(dir << 11) + (gi << 4)) << 11);

  auto stage = [&](int it, int buf) {
    char* dst = smem + buf * 20480;
#pragma unroll
    for (int g = 0; g < 4; ++g) {
      int row = (g << 4) + (w << 2) + kg;
      int c = rl ^ (row & 15);
      int k = (it << 7) + (c << 3);
      const short* src = (k < NEH) ? (Xt + (size_t)row * NEH + k)
                                   : (hcur + (size_t)row * NH + hoff + (k - NEH));
      GLD16(src, dst + (g << 12) + (w << 10));
    }
    {
      int rowB = (w << 2) + kg;
      int cB = rl ^ rowB;
      int kB = (it << 7) + (cB << 3);
      GLD16(Wbase + (size_t)rowB * 2048 + kB, dst + 16384 + (w << 10));
    }
  };

  stage(0, 0); stage(1, 1); stage(2, 2);
  f32x4 acc = {};
  int buf = 0;
  for (int it = 0; it < 16; ++it) {
    if (it < 14)      asm volatile("s_waitcnt vmcnt(10)" ::: "memory");
    else if (it == 14) asm volatile("s_waitcnt vmcnt(5)" ::: "memory");
    else               asm volatile("s_waitcnt vmcnt(0)" ::: "memory");
    __builtin_amdgcn_s_barrier();
    __builtin_amdgcn_sched_barrier(0);
    const short* As = (const short*)(smem + buf * 20480);
    const short* Bs = (const short*)(smem + buf * 20480 + 16384);
    const int rowA = (w << 4) + rl;
#pragma unroll
    for (int kk = 0; kk < 4; ++kk) {
      int chunk = (kk << 2) | kg;
      bf16x8 af = *((const bf16x8*)As + ((rowA << 4) | (chunk ^ (rowA & 15))));
      bf16x8 bf = *((const bf16x8*)Bs + ((rl << 4) | (chunk ^ rl)));
      acc = __builtin_amdgcn_mfma_f32_16x16x32_bf16(af, bf, acc, 0, 0, 0);
    }
    __builtin_amdgcn_sched_barrier(0);
    __builtin_amdgcn_s_barrier();
    if (it + 3 < 16) stage(it + 3, buf);
    buf = (buf == 2) ? 0 : buf + 1;
  }
  float* gacc = (float*)smem;                    // [64][17], overlays buf0
#pragma unroll
  for (int r = 0; r < 4; ++r)
    gacc[((w << 4) + (kg << 2) + r) * 17 + rl] = acc[r];
  __syncthreads();
  {
    const int b = tid >> 2, j2 = tid & 3;
    const float* bp = bperm + (dir << 11) + (gi << 4) + (j2 << 2);
    const float* gr = gacc + b * 17 + (j2 << 2);
    float gi_ = gr[0] + bp[0];
    float gf_ = gr[1] + bp[1];
    float gg_ = gr[2] + bp[2];
    float go_ = gr[3] + bp[3];
    const int d = ((gi >> 2) << 4) + (((gi << 2) + j2) & 15);
    const int idx = (b << 10) + hoff + d;
    float c0v = cq_old[idx];
    float si = 1.f / (1.f + __expf(-gi_));
    float sf = 1.f / (1.f + __expf(-gf_));
    float so = 1.f / (1.f + __expf(-go_));
    float tg = ftanh(gg_);
    float c2 = sf * c0v + si * tg;
    float h2 = so * ftanh(c2);
    hq_f[idx] = h2;
    cq_new[idx] = c2;
    hnext[idx] = F2B(h2);
  }
}

// ---------------------------------------------------------------------------
// Cooperative megakernel: all 64 steps, 256 blocks x 256 threads.
// ---------------------------------------------------------------------------
__global__ __launch_bounds__(256) void mega(
    const short* Wa_h, const short* Uk_h, const float* Va,
    const unsigned char* mask, const short* enc_h, const float* enc_f,
    int use_h, const short* Wcomb, const float* bperm, short* Xbuf,
    short* Hbuf, float* cq, float* hq_f, float* qbuf, float* scbuf,
    float* out_attn)
{
  cg::grid_group gg = cg::this_grid();
  __shared__ char smem[61440];
  const int blk = blockIdx.x;

#pragma unroll 1
  for (int t = 0; t < NT; ++t) {
    const short* hcur = Hbuf + (size_t)t * NB * NH;
    short* hnext = Hbuf + (size_t)(t + 1) * NB * NH;
    const float* cq_cur = cq + (t & 1) * (NB * NH);
    float* cq_nxt = cq + ((t & 1) ^ 1) * (NB * NH);
    short* Xt = Xbuf + (size_t)t * NB * NEH;

    if (blk < 64) q_phase(hcur, Wa_h, qbuf, blk, smem);
    asm volatile("s_waitcnt vmcnt(0)" ::: "memory");
    gg.sync();

    score_phase(qbuf, Uk_h, Va, mask, scbuf, blk);
    asm volatile("s_waitcnt vmcnt(0)" ::: "memory");
    gg.sync();

    ctx_phase(scbuf, enc_h, enc_f, use_h, Xt, out_attn, t, blk, smem);
    asm volatile("s_waitcnt vmcnt(0)" ::: "memory");
    gg.sync();

    gates_phase(Xt, hcur, Wcomb, bperm, cq_cur, hq_f, cq_nxt, hnext, blk, smem);
    asm volatile("s_waitcnt vmcnt(0)" ::: "memory");
    gg.sync();
  }
}

// --- standalone wrappers (fallback path if cooperative launch fails) --------
__global__ __launch_bounds__(256) void q_mm2(const short* __restrict__ hcur,
                                             const short* __restrict__ Wa_h,
                                             float* __restrict__ q) {
  __shared__ char smem[61440];
  q_phase(hcur, Wa_h, q, blockIdx.x, smem);
}
__global__ __launch_bounds__(256) void score_k(
    const float* __restrict__ q, const short* __restrict__ Uk,
    const float* __restrict__ Va, const unsigned char* __restrict__ mask,
    float* __restrict__ sc) {
  score_phase(q, Uk, Va, mask, sc, blockIdx.x);
}
__global__ __launch_bounds__(256) void ctx_k(
    const float* __restrict__ sc, const short* __restrict__ enc_h,
    const float* __restrict__ enc_f, int use_h, short* __restrict__ Xt,
    float* __restrict__ attn_out, int t) {
  __shared__ char smem[8192];
  ctx_phase(sc, enc_h, enc_f, use_h, Xt, attn_out, t, blockIdx.x, smem);
}
__global__ __launch_bounds__(256) void gates_k(
    const short* __restrict__ Xt, const short* __restrict__ hcur,
    const short* __restrict__ Wcomb, const float* __restrict__ bperm,
    const float* __restrict__ cq_old, float* __restrict__ hq_f,
    float* __restrict__ cq_new, short* __restrict__ hnext) {
  __shared__ char smem[61440];
  gates_phase(Xt, hcur, Wcomb, bperm, cq_old, hq_f, cq_new, hnext,
              blockIdx.x, smem);
}

// ---------------------------------------------------------------------------
// Fallback 64x64 tile (fp32 A staging) — used only for Uk when enc_h absent.
// ---------------------------------------------------------------------------
__device__ __forceinline__ void mm64_f32a(
    const float* __restrict__ Af, int lda, const short* __restrict__ Wg,
    int ldw, int K, short* Ch, size_t ldc, char* smem)
{
  const int tid = threadIdx.x;
  const int lane = tid & 63, w = tid >> 6;
  const int qm = (w >> 1) << 5, qn = (w & 1) << 5;
  const int kg = lane >> 4, rl = lane & 15;
  f32x4 acc[2][2] = {};
  const int nIt = K >> 6;

  auto stage = [&](int k0, int buf) {
    char* As = smem + (buf << 14);
    char* Bs = As + 8192;
#pragma unroll
    for (int p = 0; p < 2; ++p) {
      int j = tid + (p << 8);
      int row = j >> 3;
      int c = (j & 7) ^ (row & 7);
      const float* src = Af + (size_t)row * lda + k0 + (c << 3);
      float4 v0 = ((const float4*)src)[0];
      float4 v1 = ((const float4*)src)[1];
      bf16x8 pk;
      pk[0] = F2B(v0.x); pk[1] = F2B(v0.y); pk[2] = F2B(v0.z); pk[3] = F2B(v0.w);
      pk[4] = F2B(v1.x); pk[5] = F2B(v1.y); pk[6] = F2B(v1.z); pk[7] = F2B(v1.w);
      *((bf16x8*)As + j) = pk;
    }
#pragma unroll
    for (int p = 0; p < 2; ++p) {
      int j = (w << 7) + (p << 6) + lane;
      int row = j >> 3;
      int c = (j & 7) ^ (row & 7);
      GLD16(Wg + (size_t)row * ldw + k0 + (c << 3), Bs + (w << 11) + (p << 10));
    }
  };

  stage(0, 0);
  for (int it = 0; it < nIt; ++it) {
    __syncthreads();
    if (it + 1 < nIt) stage((it + 1) << 6, (it + 1) & 1);
    const short* As = (const short*)(smem + ((it & 1) << 14));
    const short* Bs = As + 4096;
#pragma unroll
    for (int kk = 0; kk < 2; ++kk) {
      bf16x8 af[2], bfr[2];
#pragma unroll
      for (int mt = 0; mt < 2; ++mt) {
        int r2 = qm + (mt << 4) + rl;
        int c = (kk << 2) + kg;
        af[mt] = *((const bf16x8*)As + ((r2 << 3) | (c ^ (r2 & 7))));
      }
#pragma unroll
      for (int nt = 0; nt < 2; ++nt) {
        int r2 = qn + (nt << 4) + rl;
        int c = (kk << 2) + kg;
        bfr[nt] = *((const bf16x8*)Bs + ((r2 << 3) | (c ^ (r2 & 7))));
      }
#pragma unroll
      for (int mt = 0; mt < 2; ++mt)
#pragma unroll
        for (int nt = 0; nt < 2; ++nt)
          acc[mt][nt] = __builtin_amdgcn_mfma_f32_16x16x32_bf16(
              af[mt], bfr[nt], acc[mt][nt], 0, 0, 0);
    }
  }
#pragma unroll
  for (int mt = 0; mt < 2; ++mt)
#pragma unroll
    for (int nt = 0; nt < 2; ++nt) {
      int cn = qn + (nt << 4) + rl;
#pragma unroll
      for (int r = 0; r < 4; ++r) {
        int rowm = qm + (mt << 4) + (kg << 2) + r;
        Ch[(size_t)rowm * ldc + cn] = F2B(acc[mt][nt][r]);
      }
    }
}

__global__ __launch_bounds__(256) void uk_mm_f32(const float* __restrict__ enc,
                                                 const short* __restrict__ Ua_h,
                                                 short* __restrict__ Uk_h) {
  __shared__ char smem[32768];
  mm64_f32a(enc + (size_t)blockIdx.y * 64 * NH, NH,
            Ua_h + (size_t)blockIdx.x * 64 * NH, NH, NH,
            Uk_h + (size_t)blockIdx.y * 64 * NH + blockIdx.x * 64, NH, smem);
}

// ---------------------------------------------------------------------------
// 128x128 bf16 tile GEMM: MODE 0 = logits, MODE 1 = Uk.
// ---------------------------------------------------------------------------
template <int MODE>
__global__ __launch_bounds__(256) void mm128(
    const short* __restrict__ A, const short* __restrict__ Bw, int nvmax,
    const float* __restrict__ bias, float* __restrict__ Cf,
    short* __restrict__ Ch)
{
  __shared__ char smem[32768];
  const int tid = threadIdx.x, lane = tid & 63, w = tid >> 6;
  const int m0 = blockIdx.y << 7;
  const int n0 = blockIdx.x << 7;
  const int qm = (w >> 1) << 6, qn = (w & 1) << 6;
  const int kg = lane >> 4, rl = lane & 15;
  f32x4 acc[4][4] = {};
  for (int k0 = 0; k0 < NH; k0 += 64) {
#pragma unroll
    for (int p = 0; p < 4; ++p) {
      int j = (((w << 2) + p) << 6) + lane;
      int row = j >> 3;
      int c = (j & 7) ^ (row & 7);
      GLD16(A + (size_t)(m0 + row) * NH + k0 + (c << 3),
            smem + (((w << 2) + p) << 10));
      int vr = n0 + row; if (vr > nvmax - 1) vr = nvmax - 1;
      GLD16(Bw + (size_t)vr * NH + k0 + (c << 3),
            smem + 16384 + (((w << 2) + p) << 10));
    }
    __syncthreads();
    const short* As = (const short*)smem;
    const short* Bs = (const short*)(smem + 16384);
#pragma unroll
    for (int kk = 0; kk < 2; ++kk) {
      bf16x8 af[4], bfr[4];
#pragma unroll
      for (int mt = 0; mt < 4; ++mt) {
        int r2 = qm + (mt << 4) + rl;
        int c = (kk << 2) + kg;
        af[mt] = *((const bf16x8*)As + ((r2 << 3) | (c ^ (r2 & 7))));
      }
#pragma unroll
      for (int nt = 0; nt < 4; ++nt) {
        int r2 = qn + (nt << 4) + rl;
        int c = (kk << 2) + kg;
        bfr[nt] = *((const bf16x8*)Bs + ((r2 << 3) | (c ^ (r2 & 7))));
      }
#pragma unroll
      for (int mt = 0; mt < 4; ++mt)
#pragma unroll
        for (int nt = 0; nt < 4; ++nt)
          acc[mt][nt] = __builtin_amdgcn_mfma_f32_16x16x32_bf16(
              af[mt], bfr[nt], acc[mt][nt], 0, 0, 0);
    }
    __syncthreads();
  }
#pragma unroll
  for (int nt = 0; nt < 4; ++nt) {
    int colv = n0 + qn + (nt << 4) + rl;
    if (colv < nvmax) {
#pragma unroll
      for (int mt = 0; mt < 4; ++mt)
#pragma unroll
        for (int r = 0; r < 4; ++r) {
          int m = m0 + qm + (mt << 4) + (kg << 2) + r;
          if (MODE == 0) {
            int b = m & 63, t = m >> 6;
            Cf[(size_t)((b << 6) + t) * NV + colv] = acc[mt][nt][r] + bias[colv];
          } else {
            Ch[(size_t)m * NH + colv] = F2B(acc[mt][nt][r]);
          }
        }
    }
  }
}

// --- small kernels ----------------------------------------------------------
__global__ __launch_bounds__(256) void f2b_k(const float* __restrict__ in,
                                             short* __restrict__ out, int n4) {
  int i = blockIdx.x * 256 + threadIdx.x;
  const int stride = gridDim.x * 256;
  for (; i < n4; i += stride) {
    float4 v = ((const float4*)in)[i];
    short4 o;
    o.x = F2B(v.x); o.y = F2B(v.y); o.z = F2B(v.z); o.w = F2B(v.w);
    ((short4*)out)[i] = o;
  }
}

__global__ __launch_bounds__(256) void perm_w(
    const float* __restrict__ Wih_f, const float* __restrict__ Whh_f,
    const float* __restrict__ Wih_b, const float* __restrict__ Whh_b,
    const float* __restrict__ bih_f, const float* __restrict__ bhh_f,
    const float* __restrict__ bih_b, const float* __restrict__ bhh_b,
    short* __restrict__ Wcomb, float* __restrict__ bias_perm)
{
  int i = blockIdx.x * 256 + threadIdx.x;        // [0, 2*2048*512)
  int k4 = i & 511;
  int np = (i >> 9) & 2047;
  int dir = i >> 20;
  int gate = np & 3, dlo = (np >> 2) & 15, dblk = np >> 6;
  int d = (dblk << 4) + dlo;
  int r = (gate << 9) + d;
  int k = k4 << 2;
  const float* Wih = dir ? Wih_b : Wih_f;
  const float* Whh = dir ? Whh_b : Whh_f;
  float4 v = (k < NEH) ? *(const float4*)(Wih + (size_t)r * NEH + k)
                       : *(const float4*)(Whh + (size_t)r * ND + (k - NEH));
  short4 o;
  o.x = F2B(v.x); o.y = F2B(v.y); o.z = F2B(v.z); o.w = F2B(v.w);
  *(short4*)(Wcomb + ((size_t)((dir << 11) + np) << 11) + k) = o;
  if (k4 == 0) {
    const float* bi = dir ? bih_b : bih_f;
    const float* bh = dir ? bhh_b : bhh_f;
    bias_perm[(dir << 11) + np] = bi[r] + bh[r];
  }
}

__global__ __launch_bounds__(256) void emb_fill(
    const float* __restrict__ emb, const int* __restrict__ target,
    const int* __restrict__ sos, short* __restrict__ Xbuf)
{
  int idx = blockIdx.x * 256 + threadIdx.x;      // [0, 64*64*128)
  int t = idx >> 13;
  int r = idx & 8191;
  int b = r >> 7, e4 = r & 127;
  int tok = (t == 0) ? sos[0] : target[b * NT + t - 1];
  float4 v = *(const float4*)(emb + (size_t)tok * NE + (e4 << 2));
  short4 o;
  o.x = F2B(v.x); o.y = F2B(v.y); o.z = F2B(v.z); o.w = F2B(v.w);
  *(short4*)(Xbuf + (size_t)(t * NB + b) * NEH + (e4 << 2)) = o;
}

__global__ __launch_bounds__(256) void init_state(
    const float* __restrict__ h0, const float* __restrict__ c0,
    float* __restrict__ hq, float* __restrict__ cq, short* __restrict__ H0) {
  int idx = blockIdx.x * 256 + threadIdx.x;
  int b = idx >> 10, dir = (idx >> 9) & 1, d = idx & 511;
  int src = dir * NB * ND + (b << 9) + d;
  float h = h0[src];
  hq[idx] = h;
  cq[idx] = c0[src];
  H0[idx] = F2B(h);
}

__global__ __launch_bounds__(256) void final_state(
    const float* __restrict__ hq, const float* __restrict__ cq,
    float* __restrict__ out_h, float* __restrict__ out_c) {
  int idx = blockIdx.x * 256 + threadIdx.x;
  int dir = idx >> 15, r = idx & 32767, b = r >> 9, d = r & 511;
  int src = b * NH + dir * ND + d;
  out_h[idx] = hq[src];
  out_c[idx] = cq[src];
}

// ---------------------------------------------------------------------------
extern "C" void kernel_launch(void* const* d_in, const int* in_sizes, int n_in,
                              void* d_out, int out_size, void* d_ws, size_t ws_size,
                              hipStream_t stream)
{
  const float* enc    = (const float*)d_in[0];
  const float* h0     = (const float*)d_in[1];
  const float* c0     = (const float*)d_in[2];
  const int*   target = (const int*)d_in[3];
  const unsigned char* mask = (const unsigned char*)d_in[4];
  const int*   sos    = (const int*)d_in[5];
  const float* emb    = (const float*)d_in[6];
  const float* Wa     = (const float*)d_in[7];
  const float* Ua     = (const float*)d_in[8];
  const float* Va     = (const float*)d_in[9];
  const float* out_W  = (const float*)d_in[10];
  const float* out_b  = (const float*)d_in[11];
  const float* Wih_f  = (const float*)d_in[12];
  const float* Whh_f  = (const float*)d_in[13];
  const float* bih_f  = (const float*)d_in[14];
  const float* bhh_f  = (const float*)d_in[15];
  const float* Wih_b  = (const float*)d_in[16];
  const float* Whh_b  = (const float*)d_in[17];
  const float* bih_b  = (const float*)d_in[18];
  const float* bhh_b  = (const float*)d_in[19];

  float* out_dec  = (float*)d_out;                       // [B][T][V]
  float* out_h    = out_dec + (size_t)NB * NT * NV;      // [2][B][D]
  float* out_c    = out_h + 2 * NB * ND;                 // [2][B][D]
  float* out_attn = out_c + 2 * NB * ND;                 // [B][T][S]

  char* base = (char*)d_ws;
  size_t off = 0;
  auto alloc = [&](size_t bytes) -> char* {
    char* p = base + off;
    off += (bytes + 255) & ~(size_t)255;
    return p;
  };
  short* Uk_h  = (short*)alloc((size_t)NB * NS * NH * 2);     // 33.5 MB
  short* ow_h  = (short*)alloc((size_t)NV * NH * 2);          // 20.5 MB
  short* Ua_h  = (short*)alloc((size_t)NH * NH * 2);
  short* Wa_h  = (short*)alloc((size_t)NH * NH * 2);
  short* Wcomb = (short*)alloc((size_t)2 * 2048 * 2048 * 2);  // 16.8 MB
  float* bperm = (float*)alloc((size_t)2 * 2048 * 4);
  float* q     = (float*)alloc((size_t)NB * NH * 4);
  float* sc    = (float*)alloc((size_t)NB * NS * 4);
  short* Xbuf  = (short*)alloc((size_t)NT * NB * NEH * 2);    // 12.6 MB
  float* hq    = (float*)alloc((size_t)NB * NH * 4);
  float* cq    = (float*)alloc((size_t)2 * NB * NH * 4);
  short* Hbuf  = (short*)alloc((size_t)(NT + 1) * NB * NH * 2); // 8.5 MB
  short* enc_h = nullptr;
  int use_h = 0;
  if (off + (size_t)NB * NS * NH * 2 <= ws_size) {
    enc_h = (short*)alloc((size_t)NB * NS * NH * 2);          // 33.5 MB
    use_h = 1;
  }
  if (off > ws_size) return;  // insufficient scratch

  // ---- setup ----
  f2b_k<<<dim3(2048), dim3(256), 0, stream>>>(out_W, ow_h, NV * NH / 4);
  f2b_k<<<dim3(1024), dim3(256), 0, stream>>>(Ua, Ua_h, NH * NH / 4);
  f2b_k<<<dim3(1024), dim3(256), 0, stream>>>(Wa, Wa_h, NH * NH / 4);
  perm_w<<<dim3(8192), dim3(256), 0, stream>>>(Wih_f, Whh_f, Wih_b, Whh_b,
                                               bih_f, bhh_f, bih_b, bhh_b,
                                               Wcomb, bperm);
  emb_fill<<<dim3(2048), dim3(256), 0, stream>>>(emb, target, sos, Xbuf);
  init_state<<<dim3(256), dim3(256), 0, stream>>>(h0, c0, hq, cq, Hbuf);
  if (use_h) {
    f2b_k<<<dim3(2048), dim3(256), 0, stream>>>(enc, enc_h, NB * NS * NH / 4);
    mm128<1><<<dim3(8, 128), dim3(256), 0, stream>>>(enc_h, Ua_h, NH, nullptr,
                                                     nullptr, Uk_h);
  } else {
    uk_mm_f32<<<dim3(16, 256), dim3(256), 0, stream>>>(enc, Ua_h, Uk_h);
  }

  // ---- recurrent loop: cooperative megakernel (fallback: 4 launches/step) --
  {
    const short* Wa_c = Wa_h; const short* Uk_c = Uk_h;
    const float* Va_c = Va; const unsigned char* mk_c = mask;
    const short* eh_c = enc_h; const float* ef_c = enc;
    int uh = use_h;
    const short* Wc_c = Wcomb; const float* bp_c = bperm;
    short* Xb = Xbuf; short* Hb = Hbuf; float* cq_p = cq; float* hq_p = hq;
    float* q_p = q; float* sc_p = sc; float* at_p = out_attn;
    void* args[] = {(void*)&Wa_c, (void*)&Uk_c, (void*)&Va_c, (void*)&mk_c,
                    (void*)&eh_c, (void*)&ef_c, (void*)&uh, (void*)&Wc_c,
                    (void*)&bp_c, (void*)&Xb, (void*)&Hb, (void*)&cq_p,
                    (void*)&hq_p, (void*)&q_p, (void*)&sc_p, (void*)&at_p};
    hipError_t err = hipLaunchCooperativeKernel((void*)mega, dim3(256),
                                                dim3(256), args, 0, stream);
    if (err != hipSuccess) {
      for (int t = 0; t < NT; ++t) {
        const short* hcur = Hbuf + (size_t)t * NB * NH;
        short* hnext = Hbuf + (size_t)(t + 1) * NB * NH;
        float* cq_cur = cq + (t & 1) * (NB * NH);
        float* cq_nxt = cq + ((t & 1) ^ 1) * (NB * NH);
        short* Xt = Xbuf + (size_t)t * NB * NEH;
        q_mm2<<<dim3(64), dim3(256), 0, stream>>>(hcur, Wa_h, q);
        score_k<<<dim3(256), dim3(256), 0, stream>>>(q, Uk_h, Va, mask, sc);
        ctx_k<<<dim3(256), dim3(256), 0, stream>>>(sc, enc_h, enc, use_h,
                                                   Xt, out_attn, t);
        gates_k<<<dim3(256), dim3(256), 0, stream>>>(Xt, hcur, Wcomb, bperm,
                                                     cq_cur, hq, cq_nxt, hnext);
      }
    }
  }

  // ---- batched vocab projection over all steps ----
  mm128<0><<<dim3(79, 32), dim3(256), 0, stream>>>(Hbuf + NB * NH, ow_h, NV,
                                                   out_b, out_dec, nullptr);
  final_state<<<dim3(256), dim3(256), 0, stream>>>(hq, cq, out_h, out_c);
}

// Round 8
// 3330.627 us; speedup vs baseline: 3.1191x; 3.1191x over previous
//
#include <hip/hip_runtime.h>

#define NB 64
#define NS 256
#define NH 1024
#define NE 512
#define NV 10000
#define NT 64
#define ND 512
#define NEH 1536

typedef __attribute__((ext_vector_type(8))) short bf16x8;
typedef __attribute__((ext_vector_type(4))) float f32x4;

__device__ __forceinline__ short F2B(float f) {
  unsigned u = __float_as_uint(f);
  return (short)((u + 0x7fffu + ((u >> 16) & 1u)) >> 16);
}
__device__ __forceinline__ float B2F(short s) {
  return __uint_as_float(((unsigned)(unsigned short)s) << 16);
}
__device__ __forceinline__ float ftanh(float x) {
  float e = __expf(2.f * x);                 // inf for big x -> rcp -> 0 -> 1
  return 1.f - 2.f * __builtin_amdgcn_rcpf(e + 1.f);
}

#define GLD16(src, dst)                                                        \
  __builtin_amdgcn_global_load_lds(                                            \
      (const __attribute__((address_space(1))) void*)(src),                    \
      (__attribute__((address_space(3))) void*)(dst), 16, 0, 0)

// UkT packed layout index (bf16 elements): ((b*128 + h/8)*256 + s)*8 + h%8
__device__ __forceinline__ size_t ukt_idx(int b, int s, int h) {
  return ((((size_t)b * 128 + (h >> 3)) << 8) + s) * 8 + (h & 7);
}

// ---------------------------------------------------------------------------
// Kernel S: per-block (b, hq): q-quarter matvec + partial scores.
// psc[hq][b][s] = sum_{h in quarter} Va[h]*tanh(q[b,h]+Uk[b,s,h])
// ---------------------------------------------------------------------------
__global__ __launch_bounds__(256) void score_q(
    const short* __restrict__ Hcur,   // [B][NH] bf16
    const short* __restrict__ Wp,     // packed [128 k8][1024 n][8 kk] bf16
    const short* __restrict__ UkT,    // packed [B][128 h8][256 s][8 hh] bf16
    const float* __restrict__ Va,
    float* __restrict__ psc)          // [4][B][S]
{
  __shared__ float hs[NH];
  __shared__ float qs[256];
  __shared__ float vs[256];
  const int tid = threadIdx.x;
  const int b = blockIdx.x >> 2, hq = blockIdx.x & 3;

  {
    short4 hv = *(const short4*)(Hcur + b * NH + (tid << 2));
    hs[(tid << 2) + 0] = B2F(hv.x);
    hs[(tid << 2) + 1] = B2F(hv.y);
    hs[(tid << 2) + 2] = B2F(hv.z);
    hs[(tid << 2) + 3] = B2F(hv.w);
    vs[tid] = Va[(hq << 8) + tid];
  }
  __syncthreads();

  // matvec: q[b, hq*256+tid] = sum_k hs[k] * Wa[n,k]
  {
    const int n = (hq << 8) + tid;
    float acc = 0.f;
#pragma unroll 4
    for (int k8 = 0; k8 < 128; ++k8) {
      bf16x8 wv = *((const bf16x8*)Wp + ((size_t)k8 << 10) + n);
      const float* hp = hs + (k8 << 3);
#pragma unroll
      for (int j = 0; j < 8; ++j) acc += hp[j] * B2F(wv[j]);
    }
    qs[tid] = acc;
  }
  __syncthreads();

  // partial score for s = tid over this h-quarter
  {
    float a = 0.f;
    const bf16x8* up = (const bf16x8*)UkT +
                       (((size_t)b * 128 + (hq << 5)) << 8) + tid;
#pragma unroll 1
    for (int h8 = 0; h8 < 32; ++h8) {
      bf16x8 uv = up[(size_t)h8 << 8];
      const float* qp = qs + (h8 << 3);
      const float* vp = vs + (h8 << 3);
#pragma unroll
      for (int j = 0; j < 8; ++j)
        a += vp[j] * ftanh(qp[j] + B2F(uv[j]));
    }
    psc[(((hq) << 6) + b) * 256 + tid] = a;
  }
}

// ---------------------------------------------------------------------------
// Kernel C: sum partials + mask + softmax + ctx. 256 blocks = (b, qh).
// ---------------------------------------------------------------------------
__global__ __launch_bounds__(256) void ctx_soft2(
    const float* __restrict__ psc, const unsigned char* __restrict__ mask,
    const short* __restrict__ enc_h, const float* __restrict__ enc_f,
    int use_h, short* __restrict__ Xt, float* __restrict__ attn_out, int t)
{
  const int tid = threadIdx.x;
  const int b = blockIdx.x >> 2, qh = blockIdx.x & 3;
  __shared__ float red[4];
  __shared__ float ws[NS];
  __shared__ float4 red4[256];
  float v = psc[(b << 8) + tid] + psc[(64 + b) * 256 + tid] +
            psc[(128 + b) * 256 + tid] + psc[(192 + b) * 256 + tid];
  if (mask[(b << 8) + tid]) v = -__builtin_inff();
  float m = v;
#pragma unroll
  for (int o = 32; o; o >>= 1) m = fmaxf(m, __shfl_down(m, o));
  if ((tid & 63) == 0) red[tid >> 6] = m;
  __syncthreads();
  m = fmaxf(fmaxf(red[0], red[1]), fmaxf(red[2], red[3]));
  float e = __expf(v - m);
  float su = e;
#pragma unroll
  for (int o = 32; o; o >>= 1) su += __shfl_down(su, o);
  __syncthreads();
  if ((tid & 63) == 0) red[tid >> 6] = su;
  __syncthreads();
  su = red[0] + red[1] + red[2] + red[3];
  float wgt = e / su;
  ws[tid] = wgt;
  if (qh == 0) attn_out[((size_t)b * NT + t) * NS + tid] = wgt;
  __syncthreads();
  const int w = tid >> 6, l = tid & 63;
  const int h = (qh << 8) + (l << 2);
  const int s0 = w << 6;
  float4 a = make_float4(0.f, 0.f, 0.f, 0.f);
  if (use_h) {
    const short* ep = enc_h + ((size_t)b * NS + s0) * NH + h;
    for (int s = 0; s < 64; ++s) {
      short4 vv = *(const short4*)(ep + (size_t)s * NH);
      float wv = ws[s0 + s];
      a.x += wv * B2F(vv.x); a.y += wv * B2F(vv.y);
      a.z += wv * B2F(vv.z); a.w += wv * B2F(vv.w);
    }
  } else {
    const float* ep = enc_f + ((size_t)b * NS + s0) * NH + h;
    for (int s = 0; s < 64; ++s) {
      float4 vv = *(const float4*)(ep + (size_t)s * NH);
      float wv = ws[s0 + s];
      a.x += wv * vv.x; a.y += wv * vv.y; a.z += wv * vv.z; a.w += wv * vv.w;
    }
  }
  red4[(w << 6) + l] = a;
  __syncthreads();
  if (tid < 64) {
    float4 r0 = red4[tid], r1 = red4[64 + tid], r2 = red4[128 + tid],
           r3 = red4[192 + tid];
    short4 o;
    o.x = F2B(r0.x + r1.x + r2.x + r3.x);
    o.y = F2B(r0.y + r1.y + r2.y + r3.y);
    o.z = F2B(r0.z + r1.z + r2.z + r3.z);
    o.w = F2B(r0.w + r1.w + r2.w + r3.w);
    *(short4*)(Xt + (size_t)b * NEH + NE + (qh << 8) + (tid << 2)) = o;
  }
}

// ---------------------------------------------------------------------------
// Kernel G: pipelined gates GEMM + LSTM cell (verbatim from Round 5 gates_v2).
// ---------------------------------------------------------------------------
__global__ __launch_bounds__(256) void gates_k(
    const short* __restrict__ Xt, const short* __restrict__ hcur,
    const short* __restrict__ Wcomb, const float* __restrict__ bperm,
    const float* __restrict__ cq_old, float* __restrict__ hq_f,
    float* __restrict__ cq_new, short* __restrict__ hnext)
{
  __shared__ char smem[61440];
  const int tid = threadIdx.x, lane = tid & 63, w = tid >> 6;
  const int kg = lane >> 4, rl = lane & 15;
  const int dir = blockIdx.x >> 7, gi = blockIdx.x & 127;
  const int hoff = dir << 9;
  const short* Wbase = Wcomb + (((size_t)(dir << 11) + (gi << 4)) << 11);

  auto stage = [&](int it, int buf) {
    char* dst = smem + buf * 20480;
#pragma unroll
    for (int g = 0; g < 4; ++g) {
      int row = (g << 4) + (w << 2) + kg;
      int c = rl ^ (row & 15);
      int k = (it << 7) + (c << 3);
      const short* src = (k < NEH) ? (Xt + (size_t)row * NEH + k)
                                   : (hcur + (size_t)row * NH + hoff + (k - NEH));
      GLD16(src, dst + (g << 12) + (w << 10));
    }
    {
      int rowB = (w << 2) + kg;
      int cB = rl ^ rowB;
      int kB = (it << 7) + (cB << 3);
      GLD16(Wbase + (size_t)rowB * 2048 + kB, dst + 16384 + (w << 10));
    }
  };

  stage(0, 0); stage(1, 1); stage(2, 2);
  f32x4 acc = {};
  int buf = 0;
  for (int it = 0; it < 16; ++it) {
    if (it < 14)      asm volatile("s_waitcnt vmcnt(10)" ::: "memory");
    else if (it == 14) asm volatile("s_waitcnt vmcnt(5)" ::: "memory");
    else               asm volatile("s_waitcnt vmcnt(0)" ::: "memory");
    __builtin_amdgcn_s_barrier();
    __builtin_amdgcn_sched_barrier(0);
    const short* As = (const short*)(smem + buf * 20480);
    const short* Bs = (const short*)(smem + buf * 20480 + 16384);
    const int rowA = (w << 4) + rl;
#pragma unroll
    for (int kk = 0; kk < 4; ++kk) {
      int chunk = (kk << 2) | kg;
      bf16x8 af = *((const bf16x8*)As + ((rowA << 4) | (chunk ^ (rowA & 15))));
      bf16x8 bf = *((const bf16x8*)Bs + ((rl << 4) | (chunk ^ rl)));
      acc = __builtin_amdgcn_mfma_f32_16x16x32_bf16(af, bf, acc, 0, 0, 0);
    }
    __builtin_amdgcn_sched_barrier(0);
    __builtin_amdgcn_s_barrier();
    if (it + 3 < 16) stage(it + 3, buf);
    buf = (buf == 2) ? 0 : buf + 1;
  }
  float* gacc = (float*)smem;                    // [64][17], overlays buf0
#pragma unroll
  for (int r = 0; r < 4; ++r)
    gacc[((w << 4) + (kg << 2) + r) * 17 + rl] = acc[r];
  __syncthreads();
  {
    const int b = tid >> 2, j2 = tid & 3;
    const float* bp = bperm + (dir << 11) + (gi << 4) + (j2 << 2);
    const float* gr = gacc + b * 17 + (j2 << 2);
    float gi_ = gr[0] + bp[0];
    float gf_ = gr[1] + bp[1];
    float gg_ = gr[2] + bp[2];
    float go_ = gr[3] + bp[3];
    const int d = ((gi >> 2) << 4) + (((gi << 2) + j2) & 15);
    const int idx = (b << 10) + hoff + d;
    float c0v = cq_old[idx];
    float si = 1.f / (1.f + __expf(-gi_));
    float sf = 1.f / (1.f + __expf(-gf_));
    float so = 1.f / (1.f + __expf(-go_));
    float tg = ftanh(gg_);
    float c2 = sf * c0v + si * tg;
    float h2 = so * ftanh(c2);
    hq_f[idx] = h2;
    cq_new[idx] = c2;
    hnext[idx] = F2B(h2);
  }
}

// ---------------------------------------------------------------------------
// Fallback 64x64 tile (fp32 A staging) for Uk when enc_h absent; writes UkT
// in the packed layout. m0 = batch*256+s row base, c0 = h col base.
// ---------------------------------------------------------------------------
__global__ __launch_bounds__(256) void uk_mm_f32(const float* __restrict__ enc,
                                                 const short* __restrict__ Ua_h,
                                                 short* __restrict__ UkT) {
  __shared__ char smem[32768];
  const float* Af = enc + (size_t)blockIdx.y * 64 * NH;
  const short* Wg = Ua_h + (size_t)blockIdx.x * 64 * NH;
  const int m0 = blockIdx.y * 64, c0 = blockIdx.x * 64;
  const int tid = threadIdx.x;
  const int lane = tid & 63, w = tid >> 6;
  const int qm = (w >> 1) << 5, qn = (w & 1) << 5;
  const int kg = lane >> 4, rl = lane & 15;
  f32x4 acc[2][2] = {};

  auto stage = [&](int k0, int buf) {
    char* As = smem + (buf << 14);
    char* Bs = As + 8192;
#pragma unroll
    for (int p = 0; p < 2; ++p) {
      int j = tid + (p << 8);
      int row = j >> 3;
      int c = (j & 7) ^ (row & 7);
      const float* src = Af + (size_t)row * NH + k0 + (c << 3);
      float4 v0 = ((const float4*)src)[0];
      float4 v1 = ((const float4*)src)[1];
      bf16x8 pk;
      pk[0] = F2B(v0.x); pk[1] = F2B(v0.y); pk[2] = F2B(v0.z); pk[3] = F2B(v0.w);
      pk[4] = F2B(v1.x); pk[5] = F2B(v1.y); pk[6] = F2B(v1.z); pk[7] = F2B(v1.w);
      *((bf16x8*)As + j) = pk;
    }
#pragma unroll
    for (int p = 0; p < 2; ++p) {
      int j = (w << 7) + (p << 6) + lane;
      int row = j >> 3;
      int c = (j & 7) ^ (row & 7);
      GLD16(Wg + (size_t)row * NH + k0 + (c << 3), Bs + (w << 11) + (p << 10));
    }
  };

  stage(0, 0);
  for (int it = 0; it < 16; ++it) {
    __syncthreads();
    if (it + 1 < 16) stage((it + 1) << 6, (it + 1) & 1);
    const short* As = (const short*)(smem + ((it & 1) << 14));
    const short* Bs = As + 4096;
#pragma unroll
    for (int kk = 0; kk < 2; ++kk) {
      bf16x8 af[2], bfr[2];
#pragma unroll
      for (int mt = 0; mt < 2; ++mt) {
        int r2 = qm + (mt << 4) + rl;
        int c = (kk << 2) + kg;
        af[mt] = *((const bf16x8*)As + ((r2 << 3) | (c ^ (r2 & 7))));
      }
#pragma unroll
      for (int nt = 0; nt < 2; ++nt) {
        int r2 = qn + (nt << 4) + rl;
        int c = (kk << 2) + kg;
        bfr[nt] = *((const bf16x8*)Bs + ((r2 << 3) | (c ^ (r2 & 7))));
      }
#pragma unroll
      for (int mt = 0; mt < 2; ++mt)
#pragma unroll
        for (int nt = 0; nt < 2; ++nt)
          acc[mt][nt] = __builtin_amdgcn_mfma_f32_16x16x32_bf16(
              af[mt], bfr[nt], acc[mt][nt], 0, 0, 0);
    }
  }
#pragma unroll
  for (int mt = 0; mt < 2; ++mt)
#pragma unroll
    for (int nt = 0; nt < 2; ++nt) {
      int cn = qn + (nt << 4) + rl;
#pragma unroll
      for (int r = 0; r < 4; ++r) {
        int m = m0 + qm + (mt << 4) + (kg << 2) + r;
        int h = c0 + cn;
        UkT[ukt_idx(m >> 8, m & 255, h)] = F2B(acc[mt][nt][r]);
      }
    }
}

// ---------------------------------------------------------------------------
// 128x128 bf16 tile GEMM, flattened grid + bijective XCD-chunk swizzle.
// MODE 0 = logits (fp32+bias, (t,b)->(b,t) store); MODE 1 = Uk (packed UkT).
// ---------------------------------------------------------------------------
template <int MODE>
__global__ __launch_bounds__(256) void mm128(
    const short* __restrict__ A, const short* __restrict__ Bw, int nvmax,
    const float* __restrict__ bias, float* __restrict__ Cf,
    short* __restrict__ Ch, int ntm)
{
  __shared__ char smem[32768];
  const int tid = threadIdx.x, lane = tid & 63, w = tid >> 6;
  const int chunk = gridDim.x >> 3;
  const int swz = (blockIdx.x & 7) * chunk + (blockIdx.x >> 3);
  const int m0 = (swz % ntm) << 7;
  const int n0 = (swz / ntm) << 7;
  const int qm = (w >> 1) << 6, qn = (w & 1) << 6;
  const int kg = lane >> 4, rl = lane & 15;
  f32x4 acc[4][4] = {};
  for (int k0 = 0; k0 < NH; k0 += 64) {
#pragma unroll
    for (int p = 0; p < 4; ++p) {
      int j = (((w << 2) + p) << 6) + lane;
      int row = j >> 3;
      int c = (j & 7) ^ (row & 7);
      GLD16(A + (size_t)(m0 + row) * NH + k0 + (c << 3),
            smem + (((w << 2) + p) << 10));
      int vr = n0 + row; if (vr > nvmax - 1) vr = nvmax - 1;
      GLD16(Bw + (size_t)vr * NH + k0 + (c << 3),
            smem + 16384 + (((w << 2) + p) << 10));
    }
    __syncthreads();
    const short* As = (const short*)smem;
    const short* Bs = (const short*)(smem + 16384);
#pragma unroll
    for (int kk = 0; kk < 2; ++kk) {
      bf16x8 af[4], bfr[4];
#pragma unroll
      for (int mt = 0; mt < 4; ++mt) {
        int r2 = qm + (mt << 4) + rl;
        int c = (kk << 2) + kg;
        af[mt] = *((const bf16x8*)As + ((r2 << 3) | (c ^ (r2 & 7))));
      }
#pragma unroll
      for (int nt = 0; nt < 4; ++nt) {
        int r2 = qn + (nt << 4) + rl;
        int c = (kk << 2) + kg;
        bfr[nt] = *((const bf16x8*)Bs + ((r2 << 3) | (c ^ (r2 & 7))));
      }
#pragma unroll
      for (int mt = 0; mt < 4; ++mt)
#pragma unroll
        for (int nt = 0; nt < 4; ++nt)
          acc[mt][nt] = __builtin_amdgcn_mfma_f32_16x16x32_bf16(
              af[mt], bfr[nt], acc[mt][nt], 0, 0, 0);
    }
    __syncthreads();
  }
#pragma unroll
  for (int nt = 0; nt < 4; ++nt) {
    int colv = n0 + qn + (nt << 4) + rl;
    if (colv < nvmax) {
#pragma unroll
      for (int mt = 0; mt < 4; ++mt)
#pragma unroll
        for (int r = 0; r < 4; ++r) {
          int m = m0 + qm + (mt << 4) + (kg << 2) + r;
          if (MODE == 0) {
            int b = m & 63, t = m >> 6;
            Cf[(size_t)((b << 6) + t) * NV + colv] = acc[mt][nt][r] + bias[colv];
          } else {
            Ch[ukt_idx(m >> 8, m & 255, colv)] = F2B(acc[mt][nt][r]);
          }
        }
    }
  }
}

// --- small kernels ----------------------------------------------------------
__global__ __launch_bounds__(256) void f2b_k(const float* __restrict__ in,
                                             short* __restrict__ out, int n4) {
  int i = blockIdx.x * 256 + threadIdx.x;
  const int stride = gridDim.x * 256;
  for (; i < n4; i += stride) {
    float4 v = ((const float4*)in)[i];
    short4 o;
    o.x = F2B(v.x); o.y = F2B(v.y); o.z = F2B(v.z); o.w = F2B(v.w);
    ((short4*)out)[i] = o;
  }
}

// Wp[k8][n][kk] = bf16(Wa[n][k8*8+kk]); 131072 units
__global__ __launch_bounds__(256) void wp_pack(const float* __restrict__ Wa,
                                               short* __restrict__ Wp) {
  int i = blockIdx.x * 256 + threadIdx.x;    // (k8, n)
  int k8 = i >> 10, n = i & 1023;
  const float* src = Wa + (size_t)n * NH + (k8 << 3);
  bf16x8 o;
#pragma unroll
  for (int j = 0; j < 8; ++j) o[j] = F2B(src[j]);
  *((bf16x8*)Wp + i) = o;
}

__global__ __launch_bounds__(256) void perm_w(
    const float* __restrict__ Wih_f, const float* __restrict__ Whh_f,
    const float* __restrict__ Wih_b, const float* __restrict__ Whh_b,
    const float* __restrict__ bih_f, const float* __restrict__ bhh_f,
    const float* __restrict__ bih_b, const float* __restrict__ bhh_b,
    short* __restrict__ Wcomb, float* __restrict__ bias_perm)
{
  int i = blockIdx.x * 256 + threadIdx.x;        // [0, 2*2048*512)
  int k4 = i & 511;
  int np = (i >> 9) & 2047;
  int dir = i >> 20;
  int gate = np & 3, dlo = (np >> 2) & 15, dblk = np >> 6;
  int d = (dblk << 4) + dlo;
  int r = (gate << 9) + d;
  int k = k4 << 2;
  const float* Wih = dir ? Wih_b : Wih_f;
  const float* Whh = dir ? Whh_b : Whh_f;
  float4 v = (k < NEH) ? *(const float4*)(Wih + (size_t)r * NEH + k)
                       : *(const float4*)(Whh + (size_t)r * ND + (k - NEH));
  short4 o;
  o.x = F2B(v.x); o.y = F2B(v.y); o.z = F2B(v.z); o.w = F2B(v.w);
  *(short4*)(Wcomb + ((size_t)((dir << 11) + np) << 11) + k) = o;
  if (k4 == 0) {
    const float* bi = dir ? bih_b : bih_f;
    const float* bh = dir ? bhh_b : bhh_f;
    bias_perm[(dir << 11) + np] = bi[r] + bh[r];
  }
}

__global__ __launch_bounds__(256) void emb_fill(
    const float* __restrict__ emb, const int* __restrict__ target,
    const int* __restrict__ sos, short* __restrict__ Xbuf)
{
  int idx = blockIdx.x * 256 + threadIdx.x;      // [0, 64*64*128)
  int t = idx >> 13;
  int r = idx & 8191;
  int b = r >> 7, e4 = r & 127;
  int tok = (t == 0) ? sos[0] : target[b * NT + t - 1];
  float4 v = *(const float4*)(emb + (size_t)tok * NE + (e4 << 2));
  short4 o;
  o.x = F2B(v.x); o.y = F2B(v.y); o.z = F2B(v.z); o.w = F2B(v.w);
  *(short4*)(Xbuf + (size_t)(t * NB + b) * NEH + (e4 << 2)) = o;
}

__global__ __launch_bounds__(256) void init_state(
    const float* __restrict__ h0, const float* __restrict__ c0,
    float* __restrict__ hq, float* __restrict__ cq, short* __restrict__ H0) {
  int idx = blockIdx.x * 256 + threadIdx.x;
  int b = idx >> 10, dir = (idx >> 9) & 1, d = idx & 511;
  int src = dir * NB * ND + (b << 9) + d;
  float h = h0[src];
  hq[idx] = h;
  cq[idx] = c0[src];
  H0[idx] = F2B(h);
}

__global__ __launch_bounds__(256) void final_state(
    const float* __restrict__ hq, const float* __restrict__ cq,
    float* __restrict__ out_h, float* __restrict__ out_c) {
  int idx = blockIdx.x * 256 + threadIdx.x;
  int dir = idx >> 15, r = idx & 32767, b = r >> 9, d = r & 511;
  int src = b * NH + dir * ND + d;
  out_h[idx] = hq[src];
  out_c[idx] = cq[src];
}

// ---------------------------------------------------------------------------
extern "C" void kernel_launch(void* const* d_in, const int* in_sizes, int n_in,
                              void* d_out, int out_size, void* d_ws, size_t ws_size,
                              hipStream_t stream)
{
  const float* enc    = (const float*)d_in[0];
  const float* h0     = (const float*)d_in[1];
  const float* c0     = (const float*)d_in[2];
  const int*   target = (const int*)d_in[3];
  const unsigned char* mask = (const unsigned char*)d_in[4];
  const int*   sos    = (const int*)d_in[5];
  const float* emb    = (const float*)d_in[6];
  const float* Wa     = (const float*)d_in[7];
  const float* Ua     = (const float*)d_in[8];
  const float* Va     = (const float*)d_in[9];
  const float* out_W  = (const float*)d_in[10];
  const float* out_b  = (const float*)d_in[11];
  const float* Wih_f  = (const float*)d_in[12];
  const float* Whh_f  = (const float*)d_in[13];
  const float* bih_f  = (const float*)d_in[14];
  const float* bhh_f  = (const float*)d_in[15];
  const float* Wih_b  = (const float*)d_in[16];
  const float* Whh_b  = (const float*)d_in[17];
  const float* bih_b  = (const float*)d_in[18];
  const float* bhh_b  = (const float*)d_in[19];

  float* out_dec  = (float*)d_out;                       // [B][T][V]
  float* out_h    = out_dec + (size_t)NB * NT * NV;      // [2][B][D]
  float* out_c    = out_h + 2 * NB * ND;                 // [2][B][D]
  float* out_attn = out_c + 2 * NB * ND;                 // [B][T][S]

  char* base = (char*)d_ws;
  size_t off = 0;
  auto alloc = [&](size_t bytes) -> char* {
    char* p = base + off;
    off += (bytes + 255) & ~(size_t)255;
    return p;
  };
  short* UkT   = (short*)alloc((size_t)NB * NS * NH * 2);     // 33.5 MB packed
  short* ow_h  = (short*)alloc((size_t)NV * NH * 2);          // 20.5 MB
  short* Ua_h  = (short*)alloc((size_t)NH * NH * 2);
  short* Wp    = (short*)alloc((size_t)NH * NH * 2);          // packed WaT
  short* Wcomb = (short*)alloc((size_t)2 * 2048 * 2048 * 2);  // 16.8 MB
  float* bperm = (float*)alloc((size_t)2 * 2048 * 4);
  float* psc   = (float*)alloc((size_t)4 * NB * NS * 4);      // 256 KB
  short* Xbuf  = (short*)alloc((size_t)NT * NB * NEH * 2);    // 12.6 MB
  float* hq    = (float*)alloc((size_t)NB * NH * 4);
  float* cq    = (float*)alloc((size_t)2 * NB * NH * 4);
  short* Hbuf  = (short*)alloc((size_t)(NT + 1) * NB * NH * 2); // 8.5 MB
  short* enc_h = nullptr;
  int use_h = 0;
  if (off + (size_t)NB * NS * NH * 2 <= ws_size) {
    enc_h = (short*)alloc((size_t)NB * NS * NH * 2);          // 33.5 MB
    use_h = 1;
  }
  if (off > ws_size) return;  // insufficient scratch

  // ---- setup ----
  f2b_k<<<dim3(2048), dim3(256), 0, stream>>>(out_W, ow_h, NV * NH / 4);
  f2b_k<<<dim3(1024), dim3(256), 0, stream>>>(Ua, Ua_h, NH * NH / 4);
  wp_pack<<<dim3(512), dim3(256), 0, stream>>>(Wa, Wp);
  perm_w<<<dim3(8192), dim3(256), 0, stream>>>(Wih_f, Whh_f, Wih_b, Whh_b,
                                               bih_f, bhh_f, bih_b, bhh_b,
                                               Wcomb, bperm);
  emb_fill<<<dim3(2048), dim3(256), 0, stream>>>(emb, target, sos, Xbuf);
  init_state<<<dim3(256), dim3(256), 0, stream>>>(h0, c0, hq, cq, Hbuf);
  if (use_h) {
    f2b_k<<<dim3(2048), dim3(256), 0, stream>>>(enc, enc_h, NB * NS * NH / 4);
    mm128<1><<<dim3(1024), dim3(256), 0, stream>>>(enc_h, Ua_h, NH, nullptr,
                                                   nullptr, UkT, 128);
  } else {
    uk_mm_f32<<<dim3(16, 256), dim3(256), 0, stream>>>(enc, Ua_h, UkT);
  }

  // ---- recurrent loop: 3 kernels per step ----
  for (int t = 0; t < NT; ++t) {
    const short* hcur = Hbuf + (size_t)t * NB * NH;
    short* hnext = Hbuf + (size_t)(t + 1) * NB * NH;
    float* cq_cur = cq + (t & 1) * (NB * NH);
    float* cq_nxt = cq + ((t & 1) ^ 1) * (NB * NH);
    short* Xt = Xbuf + (size_t)t * NB * NEH;

    score_q<<<dim3(256), dim3(256), 0, stream>>>(hcur, Wp, UkT, Va, psc);
    ctx_soft2<<<dim3(256), dim3(256), 0, stream>>>(psc, mask, enc_h, enc,
                                                   use_h, Xt, out_attn, t);
    gates_k<<<dim3(256), dim3(256), 0, stream>>>(Xt, hcur, Wcomb, bperm,
                                                 cq_cur, hq, cq_nxt, hnext);
  }

  // ---- batched vocab projection over all steps ----
  mm128<0><<<dim3(2528), dim3(256), 0, stream>>>(Hbuf + NB * NH, ow_h, NV,
                                                 out_b, out_dec, nullptr, 32);
  final_state<<<dim3(256), dim3(256), 0, stream>>>(hq, cq, out_h, out_c);
}

// Round 9
// 2103.998 us; speedup vs baseline: 4.9375x; 1.5830x over previous
//
#include <hip/hip_runtime.h>

#define NB 64
#define NS 256
#define NH 1024
#define NE 512
#define NV 10000
#define NT 64
#define ND 512
#define NEH 1536

typedef __attribute__((ext_vector_type(8))) short bf16x8;
typedef __attribute__((ext_vector_type(4))) float f32x4;

__device__ __forceinline__ short F2B(float f) {
  unsigned u = __float_as_uint(f);
  return (short)((u + 0x7fffu + ((u >> 16) & 1u)) >> 16);
}
__device__ __forceinline__ float B2F(short s) {
  return __uint_as_float(((unsigned)(unsigned short)s) << 16);
}
__device__ __forceinline__ float ftanh(float x) {
  float e = __expf(2.f * x);                 // inf for big x -> rcp -> 0 -> 1
  return 1.f - 2.f * __builtin_amdgcn_rcpf(e + 1.f);
}

#define GLD16(src, dst)                                                        \
  __builtin_amdgcn_global_load_lds(                                            \
      (const __attribute__((address_space(1))) void*)(src),                    \
      (__attribute__((address_space(3))) void*)(dst), 16, 0, 0)

// ---------------------------------------------------------------------------
// Fallback 64x64 tile (fp32 A staging) — used only for Uk when enc_h absent.
// ---------------------------------------------------------------------------
__device__ __forceinline__ void mm64_f32a(
    const float* __restrict__ Af, int lda, const short* __restrict__ Wg,
    int ldw, int K, short* Ch, size_t ldc, char* smem)
{
  const int tid = threadIdx.x;
  const int lane = tid & 63, w = tid >> 6;
  const int qm = (w >> 1) << 5, qn = (w & 1) << 5;
  const int kg = lane >> 4, rl = lane & 15;
  f32x4 acc[2][2] = {};
  const int nIt = K >> 6;

  auto stage = [&](int k0, int buf) {
    char* As = smem + (buf << 14);
    char* Bs = As + 8192;
#pragma unroll
    for (int p = 0; p < 2; ++p) {
      int j = tid + (p << 8);
      int row = j >> 3;
      int c = (j & 7) ^ (row & 7);
      const float* src = Af + (size_t)row * lda + k0 + (c << 3);
      float4 v0 = ((const float4*)src)[0];
      float4 v1 = ((const float4*)src)[1];
      bf16x8 pk;
      pk[0] = F2B(v0.x); pk[1] = F2B(v0.y); pk[2] = F2B(v0.z); pk[3] = F2B(v0.w);
      pk[4] = F2B(v1.x); pk[5] = F2B(v1.y); pk[6] = F2B(v1.z); pk[7] = F2B(v1.w);
      *((bf16x8*)As + j) = pk;
    }
#pragma unroll
    for (int p = 0; p < 2; ++p) {
      int j = (w << 7) + (p << 6) + lane;
      int row = j >> 3;
      int c = (j & 7) ^ (row & 7);
      GLD16(Wg + (size_t)row * ldw + k0 + (c << 3), Bs + (w << 11) + (p << 10));
    }
  };

  stage(0, 0);
  for (int it = 0; it < nIt; ++it) {
    __syncthreads();
    if (it + 1 < nIt) stage((it + 1) << 6, (it + 1) & 1);
    const short* As = (const short*)(smem + ((it & 1) << 14));
    const short* Bs = As + 4096;
#pragma unroll
    for (int kk = 0; kk < 2; ++kk) {
      bf16x8 af[2], bfr[2];
#pragma unroll
      for (int mt = 0; mt < 2; ++mt) {
        int r2 = qm + (mt << 4) + rl;
        int c = (kk << 2) + kg;
        af[mt] = *((const bf16x8*)As + ((r2 << 3) | (c ^ (r2 & 7))));
      }
#pragma unroll
      for (int nt = 0; nt < 2; ++nt) {
        int r2 = qn + (nt << 4) + rl;
        int c = (kk << 2) + kg;
        bfr[nt] = *((const bf16x8*)Bs + ((r2 << 3) | (c ^ (r2 & 7))));
      }
#pragma unroll
      for (int mt = 0; mt < 2; ++mt)
#pragma unroll
        for (int nt = 0; nt < 2; ++nt)
          acc[mt][nt] = __builtin_amdgcn_mfma_f32_16x16x32_bf16(
              af[mt], bfr[nt], acc[mt][nt], 0, 0, 0);
    }
  }
#pragma unroll
  for (int mt = 0; mt < 2; ++mt)
#pragma unroll
    for (int nt = 0; nt < 2; ++nt) {
      int cn = qn + (nt << 4) + rl;
#pragma unroll
      for (int r = 0; r < 4; ++r) {
        int rowm = qm + (mt << 4) + (kg << 2) + r;
        Ch[(size_t)rowm * ldc + cn] = F2B(acc[mt][nt][r]);
      }
    }
}

__global__ __launch_bounds__(256) void uk_mm_f32(const float* __restrict__ enc,
                                                 const short* __restrict__ Ua_h,
                                                 short* __restrict__ Uk_h) {
  __shared__ char smem[32768];
  mm64_f32a(enc + (size_t)blockIdx.y * 64 * NH, NH,
            Ua_h + (size_t)blockIdx.x * 64 * NH, NH, NH,
            Uk_h + (size_t)blockIdx.y * 64 * NH + blockIdx.x * 64, NH, smem);
}

// ---------------------------------------------------------------------------
// 128x128 bf16 tile GEMM, 2-deep pipelined LDS (counted vmcnt, raw barriers).
// MODE 0 = logits (fp32 + bias, (t,b)->(b,t) store), MODE 1 = Uk (bf16 store).
// ---------------------------------------------------------------------------
template <int MODE>
__global__ __launch_bounds__(256) void mm128p(
    const short* __restrict__ A, const short* __restrict__ Bw, int nvmax,
    const float* __restrict__ bias, float* __restrict__ Cf,
    short* __restrict__ Ch)
{
  __shared__ char smem[65536];
  const int tid = threadIdx.x, lane = tid & 63, w = tid >> 6;
  const int m0 = blockIdx.y << 7;
  const int n0 = blockIdx.x << 7;
  const int qm = (w >> 1) << 6, qn = (w & 1) << 6;
  const int kg = lane >> 4, rl = lane & 15;
  f32x4 acc[4][4] = {};

  auto stage = [&](int it, int buf) {
    char* dst = smem + (buf << 15);
    const int k0 = it << 6;
#pragma unroll
    for (int p = 0; p < 4; ++p) {
      int j = (((w << 2) + p) << 6) + lane;
      int row = j >> 3;
      int c = (j & 7) ^ (row & 7);
      GLD16(A + (size_t)(m0 + row) * NH + k0 + (c << 3),
            dst + (((w << 2) + p) << 10));
      int vr = n0 + row; if (vr > nvmax - 1) vr = nvmax - 1;
      GLD16(Bw + (size_t)vr * NH + k0 + (c << 3),
            dst + 16384 + (((w << 2) + p) << 10));
    }
  };

  stage(0, 0); stage(1, 1);
  for (int it = 0; it < 16; ++it) {
    if (it < 15) asm volatile("s_waitcnt vmcnt(8)" ::: "memory");
    else         asm volatile("s_waitcnt vmcnt(0)" ::: "memory");
    __builtin_amdgcn_s_barrier();
    __builtin_amdgcn_sched_barrier(0);
    const short* As = (const short*)(smem + ((it & 1) << 15));
    const short* Bs = As + 8192;
#pragma unroll
    for (int kk = 0; kk < 2; ++kk) {
      bf16x8 af[4], bfr[4];
#pragma unroll
      for (int mt = 0; mt < 4; ++mt) {
        int r2 = qm + (mt << 4) + rl;
        int c = (kk << 2) + kg;
        af[mt] = *((const bf16x8*)As + ((r2 << 3) | (c ^ (r2 & 7))));
      }
#pragma unroll
      for (int nt = 0; nt < 4; ++nt) {
        int r2 = qn + (nt << 4) + rl;
        int c = (kk << 2) + kg;
        bfr[nt] = *((const bf16x8*)Bs + ((r2 << 3) | (c ^ (r2 & 7))));
      }
#pragma unroll
      for (int mt = 0; mt < 4; ++mt)
#pragma unroll
        for (int nt = 0; nt < 4; ++nt)
          acc[mt][nt] = __builtin_amdgcn_mfma_f32_16x16x32_bf16(
              af[mt], bfr[nt], acc[mt][nt], 0, 0, 0);
    }
    __builtin_amdgcn_sched_barrier(0);
    __builtin_amdgcn_s_barrier();
    if (it + 2 < 16) stage(it + 2, it & 1);
  }
#pragma unroll
  for (int nt = 0; nt < 4; ++nt) {
    int colv = n0 + qn + (nt << 4) + rl;
    if (colv < nvmax) {
#pragma unroll
      for (int mt = 0; mt < 4; ++mt)
#pragma unroll
        for (int r = 0; r < 4; ++r) {
          int m = m0 + qm + (mt << 4) + (kg << 2) + r;
          if (MODE == 0) {
            int b = m & 63, t = m >> 6;
            Cf[(size_t)((b << 6) + t) * NV + colv] = acc[mt][nt][r] + bias[colv];
          } else {
            Ch[(size_t)m * NH + colv] = F2B(acc[mt][nt][r]);
          }
        }
    }
  }
}

// ---------------------------------------------------------------------------
// Pipelined skinny GEMM + fused LSTM cell. Grid 256 = dir(2) x gi(128).
// ---------------------------------------------------------------------------
__global__ __launch_bounds__(256) void gates_v2(
    const short* __restrict__ Xt, const short* __restrict__ hcur,
    const short* __restrict__ Wcomb, const float* __restrict__ bperm,
    const float* __restrict__ cq_old, float* __restrict__ hq_f,
    float* __restrict__ cq_new, short* __restrict__ hnext)
{
  __shared__ char smem[61440];
  const int tid = threadIdx.x, lane = tid & 63, w = tid >> 6;
  const int kg = lane >> 4, rl = lane & 15;
  const int dir = blockIdx.x >> 7, gi = blockIdx.x & 127;
  const int hoff = dir << 9;
  const short* Wbase = Wcomb + (((size_t)(dir << 11) + (gi << 4)) << 11);

  auto stage = [&](int it, int buf) {
    char* dst = smem + buf * 20480;
#pragma unroll
    for (int g = 0; g < 4; ++g) {
      int row = (g << 4) + (w << 2) + kg;
      int c = rl ^ (row & 15);
      int k = (it << 7) + (c << 3);
      const short* src = (k < NEH) ? (Xt + (size_t)row * NEH + k)
                                   : (hcur + (size_t)row * NH + hoff + (k - NEH));
      GLD16(src, dst + (g << 12) + (w << 10));
    }
    {
      int rowB = (w << 2) + kg;
      int cB = rl ^ rowB;
      int kB = (it << 7) + (cB << 3);
      GLD16(Wbase + (size_t)rowB * 2048 + kB, dst + 16384 + (w << 10));
    }
  };

  stage(0, 0); stage(1, 1); stage(2, 2);
  f32x4 acc = {};
  int buf = 0;
  for (int it = 0; it < 16; ++it) {
    if (it < 14)      asm volatile("s_waitcnt vmcnt(10)" ::: "memory");
    else if (it == 14) asm volatile("s_waitcnt vmcnt(5)" ::: "memory");
    else               asm volatile("s_waitcnt vmcnt(0)" ::: "memory");
    __builtin_amdgcn_s_barrier();
    __builtin_amdgcn_sched_barrier(0);
    const short* As = (const short*)(smem + buf * 20480);
    const short* Bs = (const short*)(smem + buf * 20480 + 16384);
    const int rowA = (w << 4) + rl;
#pragma unroll
    for (int kk = 0; kk < 4; ++kk) {
      int chunk = (kk << 2) | kg;
      bf16x8 af = *((const bf16x8*)As + ((rowA << 4) | (chunk ^ (rowA & 15))));
      bf16x8 bf = *((const bf16x8*)Bs + ((rl << 4) | (chunk ^ rl)));
      acc = __builtin_amdgcn_mfma_f32_16x16x32_bf16(af, bf, acc, 0, 0, 0);
    }
    __builtin_amdgcn_sched_barrier(0);
    __builtin_amdgcn_s_barrier();
    if (it + 3 < 16) stage(it + 3, buf);
    buf = (buf == 2) ? 0 : buf + 1;
  }
  float* gacc = (float*)smem;                    // [64][17], overlays buf0
#pragma unroll
  for (int r = 0; r < 4; ++r)
    gacc[((w << 4) + (kg << 2) + r) * 17 + rl] = acc[r];
  __syncthreads();
  {
    const int b = tid >> 2, j2 = tid & 3;
    const float* bp = bperm + (dir << 11) + (gi << 4) + (j2 << 2);
    const float* gr = gacc + b * 17 + (j2 << 2);
    float gi_ = gr[0] + bp[0];
    float gf_ = gr[1] + bp[1];
    float gg_ = gr[2] + bp[2];
    float go_ = gr[3] + bp[3];
    const int d = ((gi >> 2) << 4) + (((gi << 2) + j2) & 15);
    const int idx = (b << 10) + hoff + d;
    float c0v = cq_old[idx];
    float si = 1.f / (1.f + __expf(-gi_));
    float sf = 1.f / (1.f + __expf(-gf_));
    float so = 1.f / (1.f + __expf(-go_));
    float tg = ftanh(gg_);
    float c2 = sf * c0v + si * tg;
    float h2 = so * ftanh(c2);
    hq_f[idx] = h2;
    cq_new[idx] = c2;
    hnext[idx] = F2B(h2);
  }
}

// ---------------------------------------------------------------------------
// Pipelined q GEMM: grid 64 blocks, M=64, N=16, K=1024, BK=128, 3-deep.
// ---------------------------------------------------------------------------
__global__ __launch_bounds__(256) void q_mm2(const short* __restrict__ hcur,
                                             const short* __restrict__ Wa_h,
                                             float* __restrict__ q)
{
  __shared__ char smem[61440];
  const int tid = threadIdx.x, lane = tid & 63, w = tid >> 6;
  const int kg = lane >> 4, rl = lane & 15;
  const int n0 = blockIdx.x << 4;
  const short* Wbase = Wa_h + (size_t)n0 * NH;

  auto stage = [&](int it, int buf) {
    char* dst = smem + buf * 20480;
#pragma unroll
    for (int g = 0; g < 4; ++g) {
      int row = (g << 4) + (w << 2) + kg;
      int c = rl ^ (row & 15);
      int k = (it << 7) + (c << 3);
      GLD16(hcur + (size_t)row * NH + k, dst + (g << 12) + (w << 10));
    }
    {
      int rowB = (w << 2) + kg;
      int cB = rl ^ rowB;
      int kB = (it << 7) + (cB << 3);
      GLD16(Wbase + (size_t)rowB * NH + kB, dst + 16384 + (w << 10));
    }
  };

  stage(0, 0); stage(1, 1); stage(2, 2);
  f32x4 acc = {};
  int buf = 0;
  for (int it = 0; it < 8; ++it) {
    if (it < 6)       asm volatile("s_waitcnt vmcnt(10)" ::: "memory");
    else if (it == 6) asm volatile("s_waitcnt vmcnt(5)" ::: "memory");
    else              asm volatile("s_waitcnt vmcnt(0)" ::: "memory");
    __builtin_amdgcn_s_barrier();
    __builtin_amdgcn_sched_barrier(0);
    const short* As = (const short*)(smem + buf * 20480);
    const short* Bs = (const short*)(smem + buf * 20480 + 16384);
    const int rowA = (w << 4) + rl;
#pragma unroll
    for (int kk = 0; kk < 4; ++kk) {
      int chunk = (kk << 2) | kg;
      bf16x8 af = *((const bf16x8*)As + ((rowA << 4) | (chunk ^ (rowA & 15))));
      bf16x8 bf = *((const bf16x8*)Bs + ((rl << 4) | (chunk ^ rl)));
      acc = __builtin_amdgcn_mfma_f32_16x16x32_bf16(af, bf, acc, 0, 0, 0);
    }
    __builtin_amdgcn_sched_barrier(0);
    __builtin_amdgcn_s_barrier();
    if (it + 3 < 8) stage(it + 3, buf);
    buf = (buf == 2) ? 0 : buf + 1;
  }
#pragma unroll
  for (int r = 0; r < 4; ++r)
    q[(size_t)((w << 4) + (kg << 2) + r) * NH + n0 + rl] = acc[r];
}

// --- small kernels ----------------------------------------------------------
__global__ __launch_bounds__(256) void f2b_k(const float* __restrict__ in,
                                             short* __restrict__ out, int n4) {
  int i = blockIdx.x * 256 + threadIdx.x;
  const int stride = gridDim.x * 256;
  for (; i < n4; i += stride) {
    float4 v = ((const float4*)in)[i];
    short4 o;
    o.x = F2B(v.x); o.y = F2B(v.y); o.z = F2B(v.z); o.w = F2B(v.w);
    ((short4*)out)[i] = o;
  }
}

__global__ __launch_bounds__(256) void perm_w(
    const float* __restrict__ Wih_f, const float* __restrict__ Whh_f,
    const float* __restrict__ Wih_b, const float* __restrict__ Whh_b,
    const float* __restrict__ bih_f, const float* __restrict__ bhh_f,
    const float* __restrict__ bih_b, const float* __restrict__ bhh_b,
    short* __restrict__ Wcomb, float* __restrict__ bias_perm)
{
  int i = blockIdx.x * 256 + threadIdx.x;        // [0, 2*2048*512)
  int k4 = i & 511;
  int np = (i >> 9) & 2047;
  int dir = i >> 20;
  int gate = np & 3, dlo = (np >> 2) & 15, dblk = np >> 6;
  int d = (dblk << 4) + dlo;
  int r = (gate << 9) + d;
  int k = k4 << 2;
  const float* Wih = dir ? Wih_b : Wih_f;
  const float* Whh = dir ? Whh_b : Whh_f;
  float4 v = (k < NEH) ? *(const float4*)(Wih + (size_t)r * NEH + k)
                       : *(const float4*)(Whh + (size_t)r * ND + (k - NEH));
  short4 o;
  o.x = F2B(v.x); o.y = F2B(v.y); o.z = F2B(v.z); o.w = F2B(v.w);
  *(short4*)(Wcomb + ((size_t)((dir << 11) + np) << 11) + k) = o;
  if (k4 == 0) {
    const float* bi = dir ? bih_b : bih_f;
    const float* bh = dir ? bhh_b : bhh_f;
    bias_perm[(dir << 11) + np] = bi[r] + bh[r];
  }
}

__global__ __launch_bounds__(256) void emb_fill(
    const float* __restrict__ emb, const int* __restrict__ target,
    const int* __restrict__ sos, short* __restrict__ Xbuf)
{
  int idx = blockIdx.x * 256 + threadIdx.x;      // [0, 64*64*128)
  int t = idx >> 13;
  int r = idx & 8191;
  int b = r >> 7, e4 = r & 127;
  int tok = (t == 0) ? sos[0] : target[b * NT + t - 1];
  float4 v = *(const float4*)(emb + (size_t)tok * NE + (e4 << 2));
  short4 o;
  o.x = F2B(v.x); o.y = F2B(v.y); o.z = F2B(v.z); o.w = F2B(v.w);
  *(short4*)(Xbuf + (size_t)(t * NB + b) * NEH + (e4 << 2)) = o;
}

__global__ __launch_bounds__(256) void init_state(
    const float* __restrict__ h0, const float* __restrict__ c0,
    float* __restrict__ hq, float* __restrict__ cq, short* __restrict__ H0) {
  int idx = blockIdx.x * 256 + threadIdx.x;
  int b = idx >> 10, dir = (idx >> 9) & 1, d = idx & 511;
  int src = dir * NB * ND + (b << 9) + d;
  float h = h0[src];
  hq[idx] = h;
  cq[idx] = c0[src];
  H0[idx] = F2B(h);
}

__global__ __launch_bounds__(256) void final_state(
    const float* __restrict__ hq, const float* __restrict__ cq,
    float* __restrict__ out_h, float* __restrict__ out_c) {
  int idx = blockIdx.x * 256 + threadIdx.x;
  int dir = idx >> 15, r = idx & 32767, b = r >> 9, d = r & 511;
  int src = b * NH + dir * ND + d;
  out_h[idx] = hq[src];
  out_c[idx] = cq[src];
}

// one wave per (b,s); q[b] staged in LDS once per block (4 s per block)
// grid MUST be NB*NS/4 = 4096 blocks (b = blockIdx.x>>6).
__global__ __launch_bounds__(256) void attn_score(
    const float* __restrict__ q, const short* __restrict__ Uk,
    const float* __restrict__ Va, const unsigned char* __restrict__ mask,
    float* __restrict__ sc) {
  __shared__ float qs[NH];
  const int b = blockIdx.x >> 6;
  {
    int t4 = threadIdx.x << 2;
    *(float4*)(qs + t4) = *(const float4*)(q + (size_t)b * NH + t4);
  }
  __syncthreads();
  const int lane = threadIdx.x & 63, wid = threadIdx.x >> 6;
  const int bs = (blockIdx.x << 2) + wid;
  const short* ukp = Uk + (size_t)bs * NH;
  float acc = 0.f;
#pragma unroll
  for (int i = 0; i < 2; ++i) {
    int h = (i << 9) + (lane << 3);
    bf16x8 uv = *(const bf16x8*)(ukp + h);
    float4 q0 = *(const float4*)(qs + h);
    float4 q1 = *(const float4*)(qs + h + 4);
    float4 v0 = *(const float4*)(Va + h);
    float4 v1 = *(const float4*)(Va + h + 4);
    acc += v0.x * ftanh(q0.x + B2F(uv[0]));
    acc += v0.y * ftanh(q0.y + B2F(uv[1]));
    acc += v0.z * ftanh(q0.z + B2F(uv[2]));
    acc += v0.w * ftanh(q0.w + B2F(uv[3]));
    acc += v1.x * ftanh(q1.x + B2F(uv[4]));
    acc += v1.y * ftanh(q1.y + B2F(uv[5]));
    acc += v1.z * ftanh(q1.z + B2F(uv[6]));
    acc += v1.w * ftanh(q1.w + B2F(uv[7]));
  }
#pragma unroll
  for (int o = 32; o; o >>= 1) acc += __shfl_down(acc, o);
  if (lane == 0) sc[bs] = mask[bs] ? -__builtin_inff() : acc;
}

// 256 blocks x 512 threads: (b, h-quarter) softmax + ctx -> Xt[:, E:E+H]
__global__ __launch_bounds__(512) void ctx_soft(
    const float* __restrict__ sc, const short* __restrict__ enc_h,
    const float* __restrict__ enc_f, int use_h,
    short* __restrict__ Xt, float* __restrict__ attn_out, int t) {
  const int tid = threadIdx.x;
  const int b = blockIdx.x >> 2, qh = blockIdx.x & 3;
  __shared__ float red[8];
  __shared__ float ws[NS];
  __shared__ float4 red4[512];
  const int s8 = tid & 255;
  float v = sc[b * NS + s8];
  float m = v;
#pragma unroll
  for (int o = 32; o; o >>= 1) m = fmaxf(m, __shfl_down(m, o));
  if ((tid & 63) == 0) red[tid >> 6] = m;
  __syncthreads();
  m = fmaxf(fmaxf(fmaxf(red[0], red[1]), fmaxf(red[2], red[3])),
            fmaxf(fmaxf(red[4], red[5]), fmaxf(red[6], red[7])));
  float e = __expf(v - m);
  float su = e;
#pragma unroll
  for (int o = 32; o; o >>= 1) su += __shfl_down(su, o);
  __syncthreads();
  if ((tid & 63) == 0) red[tid >> 6] = su;
  __syncthreads();
  su = red[0] + red[1] + red[2] + red[3];
  float wgt = e / su;
  ws[s8] = wgt;                       // duplicate identical writes are benign
  if (qh == 0 && tid < 256) attn_out[((size_t)b * NT + t) * NS + tid] = wgt;
  __syncthreads();
  const int w8 = tid >> 6, l = tid & 63;
  const int h = (qh << 8) + (l << 2);
  const int s0 = w8 << 5;
  float4 a = make_float4(0.f, 0.f, 0.f, 0.f);
  if (use_h) {
    const short* ep = enc_h + ((size_t)b * NS + s0) * NH + h;
    for (int s = 0; s < 32; ++s) {
      short4 vv = *(const short4*)(ep + (size_t)s * NH);
      float wv = ws[s0 + s];
      a.x += wv * B2F(vv.x); a.y += wv * B2F(vv.y);
      a.z += wv * B2F(vv.z); a.w += wv * B2F(vv.w);
    }
  } else {
    const float* ep = enc_f + ((size_t)b * NS + s0) * NH + h;
    for (int s = 0; s < 32; ++s) {
      float4 vv = *(const float4*)(ep + (size_t)s * NH);
      float wv = ws[s0 + s];
      a.x += wv * vv.x; a.y += wv * vv.y; a.z += wv * vv.z; a.w += wv * vv.w;
    }
  }
  red4[(w8 << 6) + l] = a;
  __syncthreads();
  if (tid < 64) {
    float sx = 0.f, sy = 0.f, sz = 0.f, sw = 0.f;
#pragma unroll
    for (int k = 0; k < 8; ++k) {
      float4 r = red4[(k << 6) + tid];
      sx += r.x; sy += r.y; sz += r.z; sw += r.w;
    }
    short4 o;
    o.x = F2B(sx); o.y = F2B(sy); o.z = F2B(sz); o.w = F2B(sw);
    *(short4*)(Xt + (size_t)b * NEH + NE + (qh << 8) + (tid << 2)) = o;
  }
}

// ---------------------------------------------------------------------------
extern "C" void kernel_launch(void* const* d_in, const int* in_sizes, int n_in,
                              void* d_out, int out_size, void* d_ws, size_t ws_size,
                              hipStream_t stream)
{
  const float* enc    = (const float*)d_in[0];
  const float* h0     = (const float*)d_in[1];
  const float* c0     = (const float*)d_in[2];
  const int*   target = (const int*)d_in[3];
  const unsigned char* mask = (const unsigned char*)d_in[4];
  const int*   sos    = (const int*)d_in[5];
  const float* emb    = (const float*)d_in[6];
  const float* Wa     = (const float*)d_in[7];
  const float* Ua     = (const float*)d_in[8];
  const float* Va     = (const float*)d_in[9];
  const float* out_W  = (const float*)d_in[10];
  const float* out_b  = (const float*)d_in[11];
  const float* Wih_f  = (const float*)d_in[12];
  const float* Whh_f  = (const float*)d_in[13];
  const float* bih_f  = (const float*)d_in[14];
  const float* bhh_f  = (const float*)d_in[15];
  const float* Wih_b  = (const float*)d_in[16];
  const float* Whh_b  = (const float*)d_in[17];
  const float* bih_b  = (const float*)d_in[18];
  const float* bhh_b  = (const float*)d_in[19];

  float* out_dec  = (float*)d_out;                       // [B][T][V]
  float* out_h    = out_dec + (size_t)NB * NT * NV;      // [2][B][D]
  float* out_c    = out_h + 2 * NB * ND;                 // [2][B][D]
  float* out_attn = out_c + 2 * NB * ND;                 // [B][T][S]

  char* base = (char*)d_ws;
  size_t off = 0;
  auto alloc = [&](size_t bytes) -> char* {
    char* p = base + off;
    off += (bytes + 255) & ~(size_t)255;
    return p;
  };
  short* Uk_h  = (short*)alloc((size_t)NB * NS * NH * 2);     // 33.5 MB
  short* ow_h  = (short*)alloc((size_t)NV * NH * 2);          // 20.5 MB
  short* Ua_h  = (short*)alloc((size_t)NH * NH * 2);
  short* Wa_h  = (short*)alloc((size_t)NH * NH * 2);
  short* Wcomb = (short*)alloc((size_t)2 * 2048 * 2048 * 2);  // 16.8 MB
  float* bperm = (float*)alloc((size_t)2 * 2048 * 4);
  float* q     = (float*)alloc((size_t)NB * NH * 4);
  float* sc    = (float*)alloc((size_t)NB * NS * 4);
  short* Xbuf  = (short*)alloc((size_t)NT * NB * NEH * 2);    // 12.6 MB
  float* hq    = (float*)alloc((size_t)NB * NH * 4);
  float* cq    = (float*)alloc((size_t)2 * NB * NH * 4);
  short* Hbuf  = (short*)alloc((size_t)(NT + 1) * NB * NH * 2); // 8.5 MB
  short* enc_h = nullptr;
  int use_h = 0;
  if (off + (size_t)NB * NS * NH * 2 <= ws_size) {
    enc_h = (short*)alloc((size_t)NB * NS * NH * 2);          // 33.5 MB
    use_h = 1;
  }
  if (off > ws_size) return;  // insufficient scratch

  // ---- setup ----
  f2b_k<<<dim3(2048), dim3(256), 0, stream>>>(out_W, ow_h, NV * NH / 4);
  f2b_k<<<dim3(1024), dim3(256), 0, stream>>>(Ua, Ua_h, NH * NH / 4);
  f2b_k<<<dim3(1024), dim3(256), 0, stream>>>(Wa, Wa_h, NH * NH / 4);
  perm_w<<<dim3(8192), dim3(256), 0, stream>>>(Wih_f, Whh_f, Wih_b, Whh_b,
                                               bih_f, bhh_f, bih_b, bhh_b,
                                               Wcomb, bperm);
  emb_fill<<<dim3(2048), dim3(256), 0, stream>>>(emb, target, sos, Xbuf);
  init_state<<<dim3(256), dim3(256), 0, stream>>>(h0, c0, hq, cq, Hbuf);
  if (use_h) {
    f2b_k<<<dim3(2048), dim3(256), 0, stream>>>(enc, enc_h, NB * NS * NH / 4);
    mm128p<1><<<dim3(8, 128), dim3(256), 0, stream>>>(enc_h, Ua_h, NH, nullptr,
                                                      nullptr, Uk_h);
  } else {
    uk_mm_f32<<<dim3(16, 256), dim3(256), 0, stream>>>(enc, Ua_h, Uk_h);
  }

  // ---- recurrent loop: 4 kernels per step (R5-proven shapes) ----
  for (int t = 0; t < NT; ++t) {
    const short* hcur = Hbuf + (size_t)t * NB * NH;
    short* hnext = Hbuf + (size_t)(t + 1) * NB * NH;
    float* cq_cur = cq + (t & 1) * (NB * NH);
    float* cq_nxt = cq + ((t & 1) ^ 1) * (NB * NH);
    short* Xt = Xbuf + (size_t)t * NB * NEH;

    q_mm2<<<dim3(64), dim3(256), 0, stream>>>(hcur, Wa_h, q);
    attn_score<<<dim3(4096), dim3(256), 0, stream>>>(q, Uk_h, Va, mask, sc);
    ctx_soft<<<dim3(256), dim3(512), 0, stream>>>(sc, enc_h, enc, use_h,
                                                  Xt, out_attn, t);
    gates_v2<<<dim3(256), dim3(256), 0, stream>>>(Xt, hcur, Wcomb, bperm,
                                                  cq_cur, hq, cq_nxt, hnext);
  }

  // ---- batched vocab projection over all steps ----
  mm128p<0><<<dim3(79, 32), dim3(256), 0, stream>>>(Hbuf + NB * NH, ow_h, NV,
                                                    out_b, out_dec, nullptr);
  final_state<<<dim3(256), dim3(256), 0, stream>>>(hq, cq, out_h, out_c);
}